// Round 1
// baseline (972.951 us; speedup 1.0000x reference)
//
#include <hip/hip_runtime.h>
#include <hip/hip_bf16.h>
#include <stdint.h>
#include <stddef.h>

// Problem constants (from reference)
#define SLEN 2048
#define BSZ  4
#define HSD  1024
#define FFND 4096
#define NEXP 8
#define NTOP 2
#define NTOK (SLEN*BSZ)        // 8192 tokens
#define NROW (NTOK*NTOP)       // 16384 (token,k) rows
#define NRP  (NROW + NEXP*128) // 17408 padded row capacity
#define MAXT (NROW/128 + NEXP) // 136 max 128-row tiles

typedef __hip_bfloat16 bf16;
typedef __attribute__((ext_vector_type(8))) __bf16 b8v;   // MFMA A/B frag (4 VGPR)
typedef __attribute__((ext_vector_type(4))) float f4v;    // MFMA C/D frag

// ---- workspace layout (bytes) ----
static constexpr size_t OFF_BLOCKHIST = 0;                        // int[64][8]
static constexpr size_t OFF_BLOCKBASE = 2048;                     // int[64][8]
static constexpr size_t OFF_SCHED_E   = 4096;                     // int[160]
static constexpr size_t OFF_SCHED_R   = 4736;                     // int[160]
static constexpr size_t OFF_NTILES    = 5376;                     // int
static constexpr size_t OFF_STOK      = 16384;                    // int[NRP]
static constexpr size_t OFF_SWT       = OFF_STOK + 69632;         // float[NRP]
static constexpr size_t OFF_SLOT      = OFF_SWT + 69632;          // int[NROW]
static constexpr size_t OFF_XB        = 221184;                   // bf16[NTOK][HSD]
static constexpr size_t OFF_W1T       = OFF_XB  + (size_t)NTOK*HSD*2;        // bf16[E][FFN][HS]
static constexpr size_t OFF_W2T       = OFF_W1T + (size_t)NEXP*FFND*HSD*2;   // bf16[E][HS][FFN]
static constexpr size_t OFF_H         = OFF_W2T + (size_t)NEXP*HSD*FFND*2;   // bf16[NRP][FFN]
static constexpr size_t OFF_Y         = OFF_H   + (size_t)NRP*FFND*2;        // bf16[NRP][HS]
static constexpr size_t WS_NEED       = OFF_Y   + (size_t)NRP*HSD*2;         // ~314 MiB

// ---- helpers ----
__device__ __forceinline__ void gload_lds16(const void* g, void* l) {
  __builtin_amdgcn_global_load_lds(
      (const __attribute__((address_space(1))) unsigned int*)g,
      (__attribute__((address_space(3))) unsigned int*)l, 16, 0, 0);
}

__device__ __forceinline__ f4v mfma16(b8v a, b8v b, f4v c) {
  return __builtin_amdgcn_mfma_f32_16x16x32_bf16(a, b, c, 0, 0, 0);
}

__device__ __forceinline__ float gelu_tanh(float x) {
  // jax.nn.gelu approximate=True: 0.5x(1+tanh(sqrt(2/pi)(x+0.044715x^3)))
  float u = 0.7978845608028654f * x * (1.0f + 0.044715f * x * x);
  float e = __expf(2.0f * u);
  float t = 1.0f - 2.0f / (e + 1.0f);   // tanh(u), safe at +/-inf
  return 0.5f * x * (1.0f + t);
}

// ================= routing =================
__global__ void moe_hist(const int* __restrict__ eidx, int* __restrict__ blockhist) {
  __shared__ int h[NEXP];
  int tid = threadIdx.x;
  if (tid < NEXP) h[tid] = 0;
  __syncthreads();
  int gid = blockIdx.x * 256 + tid;          // grid = 64 blocks -> 16384
  atomicAdd(&h[eidx[gid] & 7], 1);
  __syncthreads();
  if (tid < NEXP) blockhist[blockIdx.x * NEXP + tid] = h[tid];
}

__global__ void moe_plan(const int* __restrict__ blockhist, int* __restrict__ blockbase,
                         int* __restrict__ sched_e, int* __restrict__ sched_r,
                         int* __restrict__ ntiles,
                         int* __restrict__ stok, float* __restrict__ swt) {
  int tid = threadIdx.x;
  // default-fill (pad rows): token 0, weight 0
  for (int i = tid; i < NRP; i += 256) { stok[i] = 0; swt[i] = 0.0f; }
  __syncthreads();
  if (tid == 0) {
    int cnt[NEXP], off[NEXP];
    for (int e = 0; e < NEXP; ++e) {
      int c = 0;
      for (int b = 0; b < 64; ++b) c += blockhist[b * NEXP + e];
      cnt[e] = c;
    }
    int run = 0, it = 0;
    for (int e = 0; e < NEXP; ++e) {
      off[e] = run;
      int nt = (cnt[e] + 127) >> 7;
      for (int j = 0; j < nt; ++j) { sched_e[it] = e; sched_r[it] = run + j * 128; ++it; }
      run += nt << 7;
    }
    *ntiles = it;
    for (int e = 0; e < NEXP; ++e) {
      int r = off[e];
      for (int b = 0; b < 64; ++b) { blockbase[b * NEXP + e] = r; r += blockhist[b * NEXP + e]; }
    }
  }
}

__global__ void moe_scatter(const int* __restrict__ eidx, const float* __restrict__ ew,
                            const int* __restrict__ blockbase,
                            int* __restrict__ stok, float* __restrict__ swt,
                            int* __restrict__ slot) {
  __shared__ int cur[NEXP];
  int tid = threadIdx.x;
  if (tid < NEXP) cur[tid] = blockbase[blockIdx.x * NEXP + tid];
  __syncthreads();
  int gid = blockIdx.x * 256 + tid;
  int e = eidx[gid] & 7;
  int pos = atomicAdd(&cur[e], 1);
  stok[pos] = gid >> 1;          // token = gid / NTOP
  swt[pos]  = ew[gid];
  slot[gid] = pos;
}

// ================= dtype prep =================
__global__ void conv_x(const float* __restrict__ x, bf16* __restrict__ xb) {
  int gid = blockIdx.x * 256 + threadIdx.x;          // NTOK*HSD/4 threads
  float4 v = ((const float4*)x)[gid];
  alignas(8) bf16 o[4];
  o[0] = __float2bfloat16(v.x); o[1] = __float2bfloat16(v.y);
  o[2] = __float2bfloat16(v.z); o[3] = __float2bfloat16(v.w);
  ((ushort4*)xb)[gid] = *(const ushort4*)o;
}

// src [E][R][C] f32 -> dst [E][C][R] bf16
__global__ void transpose_conv(const float* __restrict__ src, bf16* __restrict__ dst,
                               int R, int C) {
  __shared__ float tile[32][33];
  int e = blockIdx.z;
  const float* s = src + (size_t)e * R * C;
  bf16* d = dst + (size_t)e * R * C;
  int c0 = blockIdx.x * 32, r0 = blockIdx.y * 32;
  int tx = threadIdx.x, ty = threadIdx.y;
  #pragma unroll
  for (int j = 0; j < 32; j += 8)
    tile[ty + j][tx] = s[(size_t)(r0 + ty + j) * C + (c0 + tx)];
  __syncthreads();
  #pragma unroll
  for (int j = 0; j < 32; j += 8)
    d[(size_t)(c0 + ty + j) * R + (r0 + tx)] = __float2bfloat16(tile[tx][ty + j]);
}

// ================= grouped GEMM =================
// C[row0..row0+128][n0..n0+128] over B^T-layout weights.
// LDS fragment-chunk layout: chunk c (1KB) holds, at lane l*16:
//   X[(c>>1)*16 + (l&15)][ (c&1)*32 + (l>>4)*8 .. +8 ]   (X = A-tile or B^T-tile)
// -> ds_read_b128 at chunk*1024 + lane*16 is exactly one MFMA fragment, conflict-free.
template<int KDIM, int NDIM, bool GATHER, bool APPLY_GELU>
__global__ __launch_bounds__(256, 2)
void moe_gemm(const bf16* __restrict__ A, const bf16* __restrict__ B,
              bf16* __restrict__ Out,
              const int* __restrict__ stok, const float* __restrict__ swt,
              const int* __restrict__ sched_e, const int* __restrict__ sched_r,
              const int* __restrict__ ntiles) {
  int rt = blockIdx.y;
  if (rt >= *ntiles) return;
  const int tid  = threadIdx.x;
  const int lane = tid & 63;
  const int wid  = tid >> 6;
  const int wm = wid & 1, wn = wid >> 1;
  const int e    = sched_e[rt];
  const int row0 = sched_r[rt];
  const int n0   = blockIdx.x * 128;

  __shared__ short lds[16384];          // 32 KB: A chunks [0,16K), B chunks [16K,32K)
  short* Ach = lds;
  short* Bch = lds + 8192;

  const int l15 = lane & 15;
  const int lq8 = (lane >> 4) << 3;     // k sub-offset 0/8/16/24
  const bf16* Bexp = B + (size_t)e * NDIM * KDIM;

  // This wave stages A chunks wid*4..+4 and B chunks wid*4..+4 each K-iter.
  const bf16* aptr[4];
  const bf16* bptr[4];
  short* aLds[4];
  short* bLds[4];
  #pragma unroll
  for (int j = 0; j < 4; ++j) {
    int c   = wid * 4 + j;              // chunk 0..15
    int kq  = (c & 1) * 32 + lq8;       // k offset in BK=64
    int xr  = (c >> 1) * 16 + l15;      // row/col-in-tile 0..127
    int grow = GATHER ? stok[row0 + xr] : (row0 + xr);
    aptr[j] = A + (size_t)grow * KDIM + kq;
    bptr[j] = Bexp + (size_t)(n0 + xr) * KDIM + kq;
    aLds[j] = Ach + c * 512;            // wave-uniform chunk base
    bLds[j] = Bch + c * 512;
  }

  f4v acc[4][4];
  #pragma unroll
  for (int mt = 0; mt < 4; ++mt)
    #pragma unroll
    for (int nt = 0; nt < 4; ++nt) acc[mt][nt] = (f4v)0.0f;

  const int KT = KDIM / 64;
  #pragma unroll 1
  for (int kt = 0; kt < KT; ++kt) {
    __syncthreads();                    // previous iter's LDS reads done
    #pragma unroll
    for (int j = 0; j < 4; ++j) {
      gload_lds16(aptr[j], aLds[j]);
      gload_lds16(bptr[j], bLds[j]);
      aptr[j] += 64; bptr[j] += 64;
    }
    __syncthreads();                    // staging drained (vmcnt) + all waves ready
    #pragma unroll
    for (int s = 0; s < 2; ++s) {
      b8v af[4], bfm[4];
      #pragma unroll
      for (int mt = 0; mt < 4; ++mt)
        af[mt] = *(const b8v*)(Ach + ((wm * 4 + mt) * 2 + s) * 512 + lane * 8);
      #pragma unroll
      for (int nt = 0; nt < 4; ++nt)
        bfm[nt] = *(const b8v*)(Bch + ((wn * 4 + nt) * 2 + s) * 512 + lane * 8);
      #pragma unroll
      for (int mt = 0; mt < 4; ++mt)
        #pragma unroll
        for (int nt = 0; nt < 4; ++nt)
          acc[mt][nt] = mfma16(af[mt], bfm[nt], acc[mt][nt]);
    }
  }

  // epilogue: C/D layout row=(lane>>4)*4+reg, col=lane&15  [m89-verified]
  const int quad = lane >> 4;
  if (APPLY_GELU) {
    #pragma unroll
    for (int mt = 0; mt < 4; ++mt)
      #pragma unroll
      for (int nt = 0; nt < 4; ++nt) {
        f4v v = acc[mt][nt];
        #pragma unroll
        for (int r = 0; r < 4; ++r) {
          int m = row0 + wm * 64 + mt * 16 + quad * 4 + r;
          int n = n0   + wn * 64 + nt * 16 + l15;
          Out[(size_t)m * NDIM + n] = __float2bfloat16(gelu_tanh(v[r]));
        }
      }
  } else {
    float wv[4][4];
    #pragma unroll
    for (int mt = 0; mt < 4; ++mt)
      #pragma unroll
      for (int r = 0; r < 4; ++r)
        wv[mt][r] = swt[row0 + wm * 64 + mt * 16 + quad * 4 + r];
    #pragma unroll
    for (int mt = 0; mt < 4; ++mt)
      #pragma unroll
      for (int nt = 0; nt < 4; ++nt) {
        f4v v = acc[mt][nt];
        #pragma unroll
        for (int r = 0; r < 4; ++r) {
          int m = row0 + wm * 64 + mt * 16 + quad * 4 + r;
          int n = n0   + wn * 64 + nt * 16 + l15;
          Out[(size_t)m * NDIM + n] = __float2bfloat16(v[r] * wv[mt][r]);
        }
      }
  }
}

// ================= combine =================
__global__ void moe_combine(const bf16* __restrict__ Y, const int* __restrict__ slot,
                            float* __restrict__ out) {
  int gid = blockIdx.x * 256 + threadIdx.x;   // NTOK*HSD/8 threads
  int t  = gid >> 7;
  int ho = (gid & 127) << 3;
  int s0 = slot[t * 2], s1 = slot[t * 2 + 1];
  b8v a = *(const b8v*)((const __bf16*)Y + (size_t)s0 * HSD + ho);
  b8v b = *(const b8v*)((const __bf16*)Y + (size_t)s1 * HSD + ho);
  float4 o0, o1;
  o0.x = (float)a[0] + (float)b[0]; o0.y = (float)a[1] + (float)b[1];
  o0.z = (float)a[2] + (float)b[2]; o0.w = (float)a[3] + (float)b[3];
  o1.x = (float)a[4] + (float)b[4]; o1.y = (float)a[5] + (float)b[5];
  o1.z = (float)a[6] + (float)b[6]; o1.w = (float)a[7] + (float)b[7];
  float4* op = (float4*)(out + (size_t)t * HSD + ho);
  op[0] = o0; op[1] = o1;
}

// ================= launch =================
extern "C" void kernel_launch(void* const* d_in, const int* in_sizes, int n_in,
                              void* d_out, int out_size, void* d_ws, size_t ws_size,
                              hipStream_t stream) {
  const float* x    = (const float*)d_in[0];
  const float* ew   = (const float*)d_in[1];
  const float* w1   = (const float*)d_in[2];
  const float* w2   = (const float*)d_in[3];
  const int*   eidx = (const int*)d_in[4];
  float* out = (float*)d_out;
  char* ws = (char*)d_ws;

  if (ws_size < WS_NEED) {              // sentinel: absmax ~3.4e38 => ws too small
    hipMemsetAsync(d_out, 0x7F, 8, stream);
    return;
  }

  int*   blockhist = (int*)(ws + OFF_BLOCKHIST);
  int*   blockbase = (int*)(ws + OFF_BLOCKBASE);
  int*   sched_e   = (int*)(ws + OFF_SCHED_E);
  int*   sched_r   = (int*)(ws + OFF_SCHED_R);
  int*   ntiles    = (int*)(ws + OFF_NTILES);
  int*   stok      = (int*)(ws + OFF_STOK);
  float* swt       = (float*)(ws + OFF_SWT);
  int*   slot      = (int*)(ws + OFF_SLOT);
  bf16*  xb        = (bf16*)(ws + OFF_XB);
  bf16*  w1t       = (bf16*)(ws + OFF_W1T);
  bf16*  w2t       = (bf16*)(ws + OFF_W2T);
  bf16*  Hbuf      = (bf16*)(ws + OFF_H);
  bf16*  Ybuf      = (bf16*)(ws + OFF_Y);

  moe_hist<<<64, 256, 0, stream>>>(eidx, blockhist);
  moe_plan<<<1, 256, 0, stream>>>(blockhist, blockbase, sched_e, sched_r, ntiles, stok, swt);
  moe_scatter<<<64, 256, 0, stream>>>(eidx, ew, blockbase, stok, swt, slot);

  conv_x<<<(NTOK * HSD / 4) / 256, 256, 0, stream>>>(x, xb);
  transpose_conv<<<dim3(FFND / 32, HSD / 32, NEXP), dim3(32, 8), 0, stream>>>(w1, w1t, HSD, FFND);
  transpose_conv<<<dim3(HSD / 32, FFND / 32, NEXP), dim3(32, 8), 0, stream>>>(w2, w2t, FFND, HSD);

  moe_gemm<HSD, FFND, true, true><<<dim3(FFND / 128, MAXT), 256, 0, stream>>>(
      xb, w1t, Hbuf, stok, swt, sched_e, sched_r, ntiles);
  moe_gemm<FFND, HSD, false, false><<<dim3(HSD / 128, MAXT), 256, 0, stream>>>(
      Hbuf, w2t, Ybuf, stok, swt, sched_e, sched_r, ntiles);

  moe_combine<<<NTOK * HSD / 8 / 256, 256, 0, stream>>>(Ybuf, slot, out);
}

// Round 2
// 743.044 us; speedup vs baseline: 1.3094x; 1.3094x over previous
//
#include <hip/hip_runtime.h>
#include <hip/hip_bf16.h>
#include <stdint.h>
#include <stddef.h>

// Problem constants (from reference)
#define SLEN 2048
#define BSZ  4
#define HSD  1024
#define FFND 4096
#define NEXP 8
#define NTOP 2
#define NTOK (SLEN*BSZ)        // 8192 tokens
#define NROW (NTOK*NTOP)       // 16384 (token,k) rows
#define NRP  (NROW + NEXP*128) // 17408 padded row capacity
#define MAXT (NROW/128 + NEXP) // 136 max 128-row tiles

typedef __hip_bfloat16 bf16;
typedef __attribute__((ext_vector_type(8))) __bf16 b8v;   // MFMA A/B frag (4 VGPR)
typedef __attribute__((ext_vector_type(4))) float f4v;    // MFMA C/D frag

// ---- workspace layout (bytes) ----
static constexpr size_t OFF_BLOCKHIST = 0;                        // int[64][8]
static constexpr size_t OFF_BLOCKBASE = 2048;                     // int[64][8]
static constexpr size_t OFF_SCHED_E   = 4096;                     // int[160]
static constexpr size_t OFF_SCHED_R   = 4736;                     // int[160]
static constexpr size_t OFF_NTILES    = 5376;                     // int
static constexpr size_t OFF_STOK      = 16384;                    // int[NRP]
static constexpr size_t OFF_SWT       = OFF_STOK + 69632;         // float[NRP]
static constexpr size_t OFF_SLOT      = OFF_SWT + 69632;          // int[NROW]
static constexpr size_t OFF_XB        = 221184;                   // bf16[NTOK][HSD]
static constexpr size_t OFF_W1T       = OFF_XB  + (size_t)NTOK*HSD*2;        // bf16[E][FFN][HS]
static constexpr size_t OFF_W2T       = OFF_W1T + (size_t)NEXP*FFND*HSD*2;   // bf16[E][HS][FFN]
static constexpr size_t OFF_H         = OFF_W2T + (size_t)NEXP*HSD*FFND*2;   // bf16[NRP][FFN]
static constexpr size_t OFF_Y         = OFF_H   + (size_t)NRP*FFND*2;        // bf16[NRP][HS]
static constexpr size_t WS_NEED       = OFF_Y   + (size_t)NRP*HSD*2;         // ~314 MiB

// ---- helpers ----
__device__ __forceinline__ void gload_lds16(const void* g, void* l) {
  __builtin_amdgcn_global_load_lds(
      (const __attribute__((address_space(1))) unsigned int*)g,
      (__attribute__((address_space(3))) unsigned int*)l, 16, 0, 0);
}

__device__ __forceinline__ f4v mfma16(b8v a, b8v b, f4v c) {
  return __builtin_amdgcn_mfma_f32_16x16x32_bf16(a, b, c, 0, 0, 0);
}

__device__ __forceinline__ float gelu_tanh(float x) {
  // jax.nn.gelu approximate=True: 0.5x(1+tanh(sqrt(2/pi)(x+0.044715x^3)))
  float u = 0.7978845608028654f * x * (1.0f + 0.044715f * x * x);
  float e = __expf(2.0f * u);
  float t = 1.0f - 2.0f / (e + 1.0f);   // tanh(u), safe at +/-inf
  return 0.5f * x * (1.0f + t);
}

// ================= routing =================
__global__ void moe_hist(const int* __restrict__ eidx, int* __restrict__ blockhist) {
  __shared__ int h[NEXP];
  int tid = threadIdx.x;
  if (tid < NEXP) h[tid] = 0;
  __syncthreads();
  int gid = blockIdx.x * 256 + tid;          // grid = 64 blocks -> 16384
  atomicAdd(&h[eidx[gid] & 7], 1);
  __syncthreads();
  if (tid < NEXP) blockhist[blockIdx.x * NEXP + tid] = h[tid];
}

__global__ void moe_plan(const int* __restrict__ blockhist, int* __restrict__ blockbase,
                         int* __restrict__ sched_e, int* __restrict__ sched_r,
                         int* __restrict__ ntiles,
                         int* __restrict__ stok, float* __restrict__ swt) {
  int tid = threadIdx.x;
  // default-fill (pad rows): token 0, weight 0
  for (int i = tid; i < NRP; i += 256) { stok[i] = 0; swt[i] = 0.0f; }
  __syncthreads();
  if (tid == 0) {
    int cnt[NEXP], off[NEXP];
    for (int e = 0; e < NEXP; ++e) {
      int c = 0;
      for (int b = 0; b < 64; ++b) c += blockhist[b * NEXP + e];
      cnt[e] = c;
    }
    int run = 0, it = 0;
    for (int e = 0; e < NEXP; ++e) {
      off[e] = run;
      int nt = (cnt[e] + 127) >> 7;
      for (int j = 0; j < nt; ++j) { sched_e[it] = e; sched_r[it] = run + j * 128; ++it; }
      run += nt << 7;
    }
    *ntiles = it;
    for (int e = 0; e < NEXP; ++e) {
      int r = off[e];
      for (int b = 0; b < 64; ++b) { blockbase[b * NEXP + e] = r; r += blockhist[b * NEXP + e]; }
    }
  }
}

__global__ void moe_scatter(const int* __restrict__ eidx, const float* __restrict__ ew,
                            const int* __restrict__ blockbase,
                            int* __restrict__ stok, float* __restrict__ swt,
                            int* __restrict__ slot) {
  __shared__ int cur[NEXP];
  int tid = threadIdx.x;
  if (tid < NEXP) cur[tid] = blockbase[blockIdx.x * NEXP + tid];
  __syncthreads();
  int gid = blockIdx.x * 256 + tid;
  int e = eidx[gid] & 7;
  int pos = atomicAdd(&cur[e], 1);
  stok[pos] = gid >> 1;          // token = gid / NTOP
  swt[pos]  = ew[gid];
  slot[gid] = pos;
}

// ================= dtype prep =================
__global__ void conv_x(const float* __restrict__ x, bf16* __restrict__ xb) {
  int gid = blockIdx.x * 256 + threadIdx.x;          // NTOK*HSD/4 threads
  float4 v = ((const float4*)x)[gid];
  alignas(8) bf16 o[4];
  o[0] = __float2bfloat16(v.x); o[1] = __float2bfloat16(v.y);
  o[2] = __float2bfloat16(v.z); o[3] = __float2bfloat16(v.w);
  ((ushort4*)xb)[gid] = *(const ushort4*)o;
}

// src [E][R][C] f32 -> dst [E][C][R] bf16
__global__ void transpose_conv(const float* __restrict__ src, bf16* __restrict__ dst,
                               int R, int C) {
  __shared__ float tile[32][33];
  int e = blockIdx.z;
  const float* s = src + (size_t)e * R * C;
  bf16* d = dst + (size_t)e * R * C;
  int c0 = blockIdx.x * 32, r0 = blockIdx.y * 32;
  int tx = threadIdx.x, ty = threadIdx.y;
  #pragma unroll
  for (int j = 0; j < 32; j += 8)
    tile[ty + j][tx] = s[(size_t)(r0 + ty + j) * C + (c0 + tx)];
  __syncthreads();
  #pragma unroll
  for (int j = 0; j < 32; j += 8)
    d[(size_t)(c0 + ty + j) * R + (r0 + tx)] = __float2bfloat16(tile[tx][ty + j]);
}

// ================= grouped GEMM =================
// C[row0..row0+128][n0..n0+128] over B^T-layout weights.
//
// LDS: each tile is row-major [128 rows][64 k-elems] bf16 (128 B/row = 8
// granules of 16 B), with granules XOR-swizzled within the row:
//   physical_granule = logical_granule ^ (row & 7)
// Staging: one global_load_lds(16B) per 8 rows; lane l covers row
// base+ (l>>3), logical granule (l&7)^(l>>3)  -> each 8-lane group reads one
// full 128-B line (coalesced), and the swizzle falls out for free because the
// LDS dest is forced to lane*16.
// Compute: frag read at row m, granule kg=(s*4+quad) -> physical kg^(m&7);
// 16 lanes of a quad hit 8 distinct start-banks x2 = 2-way aliasing (free).
template<int KDIM, int NDIM, bool GATHER, bool APPLY_GELU>
__global__ __launch_bounds__(256, 2)
void moe_gemm(const bf16* __restrict__ A, const bf16* __restrict__ B,
              bf16* __restrict__ Out,
              const int* __restrict__ stok, const float* __restrict__ swt,
              const int* __restrict__ sched_e, const int* __restrict__ sched_r,
              const int* __restrict__ ntiles) {
  int rt = blockIdx.y;
  if (rt >= *ntiles) return;
  const int tid  = threadIdx.x;
  const int lane = tid & 63;
  const int wid  = tid >> 6;
  const int wm = wid & 1, wn = wid >> 1;
  const int e    = sched_e[rt];
  const int row0 = sched_r[rt];
  const int n0   = blockIdx.x * 128;

  __shared__ short lds[16384];          // 32 KB: A tile [0,16K), B tile [16K,32K)
  short* Ach = lds;
  short* Bch = lds + 8192;

  const int l15  = lane & 15;
  const int quad = lane >> 4;
  const ushort* Aus = (const ushort*)A;
  const ushort* Bexp = (const ushort*)B + (size_t)e * NDIM * KDIM;

  // ---- staging pointers (coalesced, swizzle folded into global k-offset) ----
  const int rsub  = lane >> 3;                 // 0..7: row within instruction
  const int kgsrc = (lane & 7) ^ rsub;         // granule permutation (same line)
  const ushort* aptr[4];
  const ushort* bptr[4];
  short* aLds[4];
  short* bLds[4];
  #pragma unroll
  for (int j = 0; j < 4; ++j) {
    int i  = wid * 4 + j;                      // instruction 0..15: rows 8i..8i+7
    int xr = 8 * i + rsub;                     // row/col within tile
    int grow = GATHER ? stok[row0 + xr] : (row0 + xr);
    aptr[j] = Aus  + (size_t)grow * KDIM + kgsrc * 8;
    bptr[j] = Bexp + (size_t)(n0 + xr) * KDIM + kgsrc * 8;
    aLds[j] = Ach + i * 512;                   // wave-uniform 1 KB chunk base
    bLds[j] = Bch + i * 512;
  }

  // ---- compute-side LDS offsets (shorts), constant across K ----
  int aoff[4][2], boff[4][2];
  #pragma unroll
  for (int t = 0; t < 4; ++t) {
    int m_local = wm * 64 + t * 16 + l15;
    int n_local = wn * 64 + t * 16 + l15;
    #pragma unroll
    for (int s = 0; s < 2; ++s) {
      int kg = s * 4 + quad;
      aoff[t][s] = m_local * 64 + ((kg ^ (l15 & 7)) << 3);
      boff[t][s] = n_local * 64 + ((kg ^ (l15 & 7)) << 3);
    }
  }

  f4v acc[4][4];
  #pragma unroll
  for (int mt = 0; mt < 4; ++mt)
    #pragma unroll
    for (int nt = 0; nt < 4; ++nt) acc[mt][nt] = (f4v)0.0f;

  const int KT = KDIM / 64;
  #pragma unroll 1
  for (int kt = 0; kt < KT; ++kt) {
    __syncthreads();                    // previous iter's LDS reads done
    #pragma unroll
    for (int j = 0; j < 4; ++j) {
      gload_lds16(aptr[j], aLds[j]);
      gload_lds16(bptr[j], bLds[j]);
      aptr[j] += 64; bptr[j] += 64;
    }
    __syncthreads();                    // staging drained (vmcnt) + all waves ready
    #pragma unroll
    for (int s = 0; s < 2; ++s) {
      b8v af[4], bfm[4];
      #pragma unroll
      for (int mt = 0; mt < 4; ++mt)
        af[mt] = *(const b8v*)(Ach + aoff[mt][s]);
      #pragma unroll
      for (int nt = 0; nt < 4; ++nt)
        bfm[nt] = *(const b8v*)(Bch + boff[nt][s]);
      #pragma unroll
      for (int mt = 0; mt < 4; ++mt)
        #pragma unroll
        for (int nt = 0; nt < 4; ++nt)
          acc[mt][nt] = mfma16(af[mt], bfm[nt], acc[mt][nt]);
    }
  }

  // epilogue: C/D layout row=(lane>>4)*4+reg, col=lane&15  [m89-verified]
  if (APPLY_GELU) {
    #pragma unroll
    for (int mt = 0; mt < 4; ++mt)
      #pragma unroll
      for (int nt = 0; nt < 4; ++nt) {
        f4v v = acc[mt][nt];
        #pragma unroll
        for (int r = 0; r < 4; ++r) {
          int m = row0 + wm * 64 + mt * 16 + quad * 4 + r;
          int n = n0   + wn * 64 + nt * 16 + l15;
          Out[(size_t)m * NDIM + n] = __float2bfloat16(gelu_tanh(v[r]));
        }
      }
  } else {
    float wv[4][4];
    #pragma unroll
    for (int mt = 0; mt < 4; ++mt)
      #pragma unroll
      for (int r = 0; r < 4; ++r)
        wv[mt][r] = swt[row0 + wm * 64 + mt * 16 + quad * 4 + r];
    #pragma unroll
    for (int mt = 0; mt < 4; ++mt)
      #pragma unroll
      for (int nt = 0; nt < 4; ++nt) {
        f4v v = acc[mt][nt];
        #pragma unroll
        for (int r = 0; r < 4; ++r) {
          int m = row0 + wm * 64 + mt * 16 + quad * 4 + r;
          int n = n0   + wn * 64 + nt * 16 + l15;
          Out[(size_t)m * NDIM + n] = __float2bfloat16(v[r] * wv[mt][r]);
        }
      }
  }
}

// ================= combine =================
__global__ void moe_combine(const bf16* __restrict__ Y, const int* __restrict__ slot,
                            float* __restrict__ out) {
  int gid = blockIdx.x * 256 + threadIdx.x;   // NTOK*HSD/8 threads
  int t  = gid >> 7;
  int ho = (gid & 127) << 3;
  int s0 = slot[t * 2], s1 = slot[t * 2 + 1];
  b8v a = *(const b8v*)((const __bf16*)Y + (size_t)s0 * HSD + ho);
  b8v b = *(const b8v*)((const __bf16*)Y + (size_t)s1 * HSD + ho);
  float4 o0, o1;
  o0.x = (float)a[0] + (float)b[0]; o0.y = (float)a[1] + (float)b[1];
  o0.z = (float)a[2] + (float)b[2]; o0.w = (float)a[3] + (float)b[3];
  o1.x = (float)a[4] + (float)b[4]; o1.y = (float)a[5] + (float)b[5];
  o1.z = (float)a[6] + (float)b[6]; o1.w = (float)a[7] + (float)b[7];
  float4* op = (float4*)(out + (size_t)t * HSD + ho);
  op[0] = o0; op[1] = o1;
}

// ================= launch =================
extern "C" void kernel_launch(void* const* d_in, const int* in_sizes, int n_in,
                              void* d_out, int out_size, void* d_ws, size_t ws_size,
                              hipStream_t stream) {
  const float* x    = (const float*)d_in[0];
  const float* ew   = (const float*)d_in[1];
  const float* w1   = (const float*)d_in[2];
  const float* w2   = (const float*)d_in[3];
  const int*   eidx = (const int*)d_in[4];
  float* out = (float*)d_out;
  char* ws = (char*)d_ws;

  if (ws_size < WS_NEED) {              // sentinel: absmax ~3.4e38 => ws too small
    hipMemsetAsync(d_out, 0x7F, 8, stream);
    return;
  }

  int*   blockhist = (int*)(ws + OFF_BLOCKHIST);
  int*   blockbase = (int*)(ws + OFF_BLOCKBASE);
  int*   sched_e   = (int*)(ws + OFF_SCHED_E);
  int*   sched_r   = (int*)(ws + OFF_SCHED_R);
  int*   ntiles    = (int*)(ws + OFF_NTILES);
  int*   stok      = (int*)(ws + OFF_STOK);
  float* swt       = (float*)(ws + OFF_SWT);
  int*   slot      = (int*)(ws + OFF_SLOT);
  bf16*  xb        = (bf16*)(ws + OFF_XB);
  bf16*  w1t       = (bf16*)(ws + OFF_W1T);
  bf16*  w2t       = (bf16*)(ws + OFF_W2T);
  bf16*  Hbuf      = (bf16*)(ws + OFF_H);
  bf16*  Ybuf      = (bf16*)(ws + OFF_Y);

  moe_hist<<<64, 256, 0, stream>>>(eidx, blockhist);
  moe_plan<<<1, 256, 0, stream>>>(blockhist, blockbase, sched_e, sched_r, ntiles, stok, swt);
  moe_scatter<<<64, 256, 0, stream>>>(eidx, ew, blockbase, stok, swt, slot);

  conv_x<<<(NTOK * HSD / 4) / 256, 256, 0, stream>>>(x, xb);
  transpose_conv<<<dim3(FFND / 32, HSD / 32, NEXP), dim3(32, 8), 0, stream>>>(w1, w1t, HSD, FFND);
  transpose_conv<<<dim3(HSD / 32, FFND / 32, NEXP), dim3(32, 8), 0, stream>>>(w2, w2t, FFND, HSD);

  moe_gemm<HSD, FFND, true, true><<<dim3(FFND / 128, MAXT), 256, 0, stream>>>(
      xb, w1t, Hbuf, stok, swt, sched_e, sched_r, ntiles);
  moe_gemm<FFND, HSD, false, false><<<dim3(HSD / 128, MAXT), 256, 0, stream>>>(
      Hbuf, w2t, Ybuf, stok, swt, sched_e, sched_r, ntiles);

  moe_combine<<<NTOK * HSD / 8 / 256, 256, 0, stream>>>(Ybuf, slot, out);
}

// Round 3
// 733.637 us; speedup vs baseline: 1.3262x; 1.0128x over previous
//
#include <hip/hip_runtime.h>
#include <hip/hip_bf16.h>
#include <stdint.h>
#include <stddef.h>

// Problem constants (from reference)
#define SLEN 2048
#define BSZ  4
#define HSD  1024
#define FFND 4096
#define NEXP 8
#define NTOP 2
#define NTOK (SLEN*BSZ)        // 8192 tokens
#define NROW (NTOK*NTOP)       // 16384 (token,k) rows
#define NRP  (NROW + NEXP*128) // 17408 padded row capacity
#define MAXT (NROW/128 + NEXP) // 136 max 128-row tiles

typedef __hip_bfloat16 bf16;
typedef __attribute__((ext_vector_type(8))) __bf16 b8v;   // MFMA A/B frag (4 VGPR)
typedef __attribute__((ext_vector_type(4))) float f4v;    // MFMA C/D frag

// ---- workspace layout (bytes) ----
static constexpr size_t OFF_BLOCKHIST = 0;                        // int[64][8]
static constexpr size_t OFF_BLOCKBASE = 2048;                     // int[64][8]
static constexpr size_t OFF_SCHED_E   = 4096;                     // int[160]
static constexpr size_t OFF_SCHED_R   = 4736;                     // int[160]
static constexpr size_t OFF_NTILES    = 5376;                     // int
static constexpr size_t OFF_STOK      = 16384;                    // int[NRP]
static constexpr size_t OFF_SWT       = OFF_STOK + 69632;         // float[NRP]
static constexpr size_t OFF_SLOT      = OFF_SWT + 69632;          // int[NROW]
static constexpr size_t OFF_XB        = 221184;                   // bf16[NTOK][HSD]
static constexpr size_t OFF_W1T       = OFF_XB  + (size_t)NTOK*HSD*2;        // bf16[E][FFN][HS]
static constexpr size_t OFF_W2T       = OFF_W1T + (size_t)NEXP*FFND*HSD*2;   // bf16[E][HS][FFN]
static constexpr size_t OFF_H         = OFF_W2T + (size_t)NEXP*HSD*FFND*2;   // bf16[NRP][FFN]
static constexpr size_t OFF_Y         = OFF_H   + (size_t)NRP*FFND*2;        // (kept for WS_NEED)
static constexpr size_t WS_NEED       = OFF_Y   + (size_t)NRP*HSD*2;         // ~314 MiB (known-good)
// Split-K partials alias the xb+w1t region (dead after GEMM1):
//   Yp = bf16[2][NRP][HSD] = 71.3 MB  <=  xb(16.8) + w1t(67.1) = 83.9 MB  OK
static constexpr size_t OFF_YP        = OFF_XB;

// ---- helpers ----
__device__ __forceinline__ void gload_lds16(const void* g, void* l) {
  __builtin_amdgcn_global_load_lds(
      (const __attribute__((address_space(1))) unsigned int*)g,
      (__attribute__((address_space(3))) unsigned int*)l, 16, 0, 0);
}

__device__ __forceinline__ f4v mfma16(b8v a, b8v b, f4v c) {
  return __builtin_amdgcn_mfma_f32_16x16x32_bf16(a, b, c, 0, 0, 0);
}

__device__ __forceinline__ float gelu_tanh(float x) {
  float u = 0.7978845608028654f * x * (1.0f + 0.044715f * x * x);
  float e = __expf(2.0f * u);
  float t = 1.0f - 2.0f / (e + 1.0f);   // tanh(u), safe at +/-inf
  return 0.5f * x * (1.0f + t);
}

// ================= routing =================
__global__ void moe_hist(const int* __restrict__ eidx, int* __restrict__ blockhist) {
  __shared__ int h[NEXP];
  int tid = threadIdx.x;
  if (tid < NEXP) h[tid] = 0;
  __syncthreads();
  int gid = blockIdx.x * 256 + tid;          // grid = 64 blocks -> 16384
  atomicAdd(&h[eidx[gid] & 7], 1);
  __syncthreads();
  if (tid < NEXP) blockhist[blockIdx.x * NEXP + tid] = h[tid];
}

__global__ void moe_plan(const int* __restrict__ blockhist, int* __restrict__ blockbase,
                         int* __restrict__ sched_e, int* __restrict__ sched_r,
                         int* __restrict__ ntiles,
                         int* __restrict__ stok, float* __restrict__ swt) {
  int tid = threadIdx.x;
  for (int i = tid; i < NRP; i += 256) { stok[i] = 0; swt[i] = 0.0f; }
  __syncthreads();
  if (tid == 0) {
    int cnt[NEXP], off[NEXP];
    for (int e = 0; e < NEXP; ++e) {
      int c = 0;
      for (int b = 0; b < 64; ++b) c += blockhist[b * NEXP + e];
      cnt[e] = c;
    }
    int run = 0, it = 0;
    for (int e = 0; e < NEXP; ++e) {
      off[e] = run;
      int nt = (cnt[e] + 127) >> 7;
      for (int j = 0; j < nt; ++j) { sched_e[it] = e; sched_r[it] = run + j * 128; ++it; }
      run += nt << 7;
    }
    *ntiles = it;
    for (int e = 0; e < NEXP; ++e) {
      int r = off[e];
      for (int b = 0; b < 64; ++b) { blockbase[b * NEXP + e] = r; r += blockhist[b * NEXP + e]; }
    }
  }
}

__global__ void moe_scatter(const int* __restrict__ eidx, const float* __restrict__ ew,
                            const int* __restrict__ blockbase,
                            int* __restrict__ stok, float* __restrict__ swt,
                            int* __restrict__ slot) {
  __shared__ int cur[NEXP];
  int tid = threadIdx.x;
  if (tid < NEXP) cur[tid] = blockbase[blockIdx.x * NEXP + tid];
  __syncthreads();
  int gid = blockIdx.x * 256 + tid;
  int e = eidx[gid] & 7;
  int pos = atomicAdd(&cur[e], 1);
  stok[pos] = gid >> 1;          // token = gid / NTOP
  swt[pos]  = ew[gid];
  slot[gid] = pos;
}

// ================= dtype prep =================
__global__ void conv_x(const float* __restrict__ x, bf16* __restrict__ xb) {
  int gid = blockIdx.x * 256 + threadIdx.x;          // NTOK*HSD/4 threads
  float4 v = ((const float4*)x)[gid];
  alignas(8) bf16 o[4];
  o[0] = __float2bfloat16(v.x); o[1] = __float2bfloat16(v.y);
  o[2] = __float2bfloat16(v.z); o[3] = __float2bfloat16(v.w);
  ((ushort4*)xb)[gid] = *(const ushort4*)o;
}

// src [E][R][C] f32 -> dst [E][C][R] bf16.  64 rows x 32 cols per block;
// stores are packed uint (2x bf16): 32 lanes x 4 B = full 128-B lines.
__global__ void transpose_conv(const float* __restrict__ src, bf16* __restrict__ dst,
                               int R, int C) {
  __shared__ float tile[32][65];          // [col][row], pad breaks 64-stride
  int e = blockIdx.z;
  const float* s = src + (size_t)e * R * C;
  uint* d = (uint*)((ushort*)dst + (size_t)e * R * C);
  int c0 = blockIdx.x * 32, r0 = blockIdx.y * 64;
  int tx = threadIdx.x, ty = threadIdx.y;  // 32 x 8
  #pragma unroll
  for (int j = 0; j < 64; j += 8)
    tile[tx][ty + j] = s[(size_t)(r0 + ty + j) * C + (c0 + tx)];
  __syncthreads();
  #pragma unroll
  for (int j = 0; j < 32; j += 8) {
    int c = ty + j;
    alignas(4) bf16 p[2];
    p[0] = __float2bfloat16(tile[c][tx * 2]);
    p[1] = __float2bfloat16(tile[c][tx * 2 + 1]);
    d[(((size_t)(c0 + c) * R + r0) >> 1) + tx] = *(const uint*)p;
  }
}

// ================= grouped GEMM =================
// C[row0..+128][n0..+128], B^T-layout weights, XOR-swizzled LDS (see R1 notes).
// NSPLIT: K is split into NSPLIT chunks along blockIdx.z, each writing its own
// output buffer (partials summed in moe_combine).
// ACT: 0 = gelu->bf16 (GEMM1), 1 = plain bf16 store (GEMM2 partials).
template<int KDIM, int NDIM, int NSPLIT, bool GATHER, int ACT>
__global__ __launch_bounds__(256, 4)
void moe_gemm(const bf16* __restrict__ A, const bf16* __restrict__ B,
              bf16* __restrict__ OutBase,
              const int* __restrict__ stok,
              const int* __restrict__ sched_e, const int* __restrict__ sched_r,
              const int* __restrict__ ntiles) {
  int rt = blockIdx.y;
  if (rt >= *ntiles) return;
  const int tid  = threadIdx.x;
  const int lane = tid & 63;
  const int wid  = tid >> 6;
  const int wm = wid & 1, wn = wid >> 1;
  const int e    = sched_e[rt];
  const int row0 = sched_r[rt];
  const int n0   = blockIdx.x * 128;
  const int z    = blockIdx.z;
  const int kbase = z * (KDIM / NSPLIT);
  bf16* Out = OutBase + (size_t)z * NRP * NDIM;

  __shared__ short lds[16384];          // 32 KB: A tile [0,16K), B tile [16K,32K)
  short* Ach = lds;
  short* Bch = lds + 8192;

  const int l15  = lane & 15;
  const int quad = lane >> 4;
  const ushort* Aus = (const ushort*)A;
  const ushort* Bexp = (const ushort*)B + (size_t)e * NDIM * KDIM;

  // ---- staging pointers (coalesced, swizzle folded into global k-offset) ----
  const int rsub  = lane >> 3;                 // 0..7: row within instruction
  const int kgsrc = (lane & 7) ^ rsub;         // granule permutation (same line)
  const ushort* aptr[4];
  const ushort* bptr[4];
  short* aLds[4];
  short* bLds[4];
  #pragma unroll
  for (int j = 0; j < 4; ++j) {
    int i  = wid * 4 + j;                      // instruction 0..15: rows 8i..8i+7
    int xr = 8 * i + rsub;                     // row/col within tile
    int grow = GATHER ? stok[row0 + xr] : (row0 + xr);
    aptr[j] = Aus  + (size_t)grow * KDIM + kbase + kgsrc * 8;
    bptr[j] = Bexp + (size_t)(n0 + xr) * KDIM + kbase + kgsrc * 8;
    aLds[j] = Ach + i * 512;                   // wave-uniform 1 KB chunk base
    bLds[j] = Bch + i * 512;
  }

  // ---- compute-side LDS offsets (shorts), constant across K ----
  int aoff[4][2], boff[4][2];
  #pragma unroll
  for (int t = 0; t < 4; ++t) {
    int m_local = wm * 64 + t * 16 + l15;
    int n_local = wn * 64 + t * 16 + l15;
    #pragma unroll
    for (int s = 0; s < 2; ++s) {
      int kg = s * 4 + quad;
      aoff[t][s] = m_local * 64 + ((kg ^ (l15 & 7)) << 3);
      boff[t][s] = n_local * 64 + ((kg ^ (l15 & 7)) << 3);
    }
  }

  f4v acc[4][4];
  #pragma unroll
  for (int mt = 0; mt < 4; ++mt)
    #pragma unroll
    for (int nt = 0; nt < 4; ++nt) acc[mt][nt] = (f4v)0.0f;

  const int KT = KDIM / 64 / NSPLIT;
  #pragma unroll 1
  for (int kt = 0; kt < KT; ++kt) {
    __syncthreads();                    // previous iter's LDS reads done
    #pragma unroll
    for (int j = 0; j < 4; ++j) {
      gload_lds16(aptr[j], aLds[j]);
      gload_lds16(bptr[j], bLds[j]);
      aptr[j] += 64; bptr[j] += 64;
    }
    __syncthreads();                    // staging drained + all waves ready
    #pragma unroll
    for (int s = 0; s < 2; ++s) {
      b8v af[4], bfm[4];
      #pragma unroll
      for (int mt = 0; mt < 4; ++mt)
        af[mt] = *(const b8v*)(Ach + aoff[mt][s]);
      #pragma unroll
      for (int nt = 0; nt < 4; ++nt)
        bfm[nt] = *(const b8v*)(Bch + boff[nt][s]);
      #pragma unroll
      for (int mt = 0; mt < 4; ++mt)
        #pragma unroll
        for (int nt = 0; nt < 4; ++nt)
          acc[mt][nt] = mfma16(af[mt], bfm[nt], acc[mt][nt]);
    }
  }

  // epilogue: C/D layout row=(lane>>4)*4+reg, col=lane&15  [m89-verified]
  #pragma unroll
  for (int mt = 0; mt < 4; ++mt)
    #pragma unroll
    for (int nt = 0; nt < 4; ++nt) {
      f4v v = acc[mt][nt];
      #pragma unroll
      for (int r = 0; r < 4; ++r) {
        int m = row0 + wm * 64 + mt * 16 + quad * 4 + r;
        int n = n0   + wn * 64 + nt * 16 + l15;
        float o = (ACT == 0) ? gelu_tanh(v[r]) : v[r];
        Out[(size_t)m * NDIM + n] = __float2bfloat16(o);
      }
    }
}

// ================= combine =================
// out[t] = swt[s0]*(Yp0[s0]+Yp1[s0]) + swt[s1]*(Yp0[s1]+Yp1[s1])
__global__ void moe_combine(const bf16* __restrict__ Yp, const float* __restrict__ swt,
                            const int* __restrict__ slot, float* __restrict__ out) {
  int gid = blockIdx.x * 256 + threadIdx.x;   // NTOK*HSD/8 threads
  int t  = gid >> 7;
  int ho = (gid & 127) << 3;
  int s0 = slot[t * 2], s1 = slot[t * 2 + 1];
  float w0 = swt[s0], w1 = swt[s1];
  const __bf16* Y0 = (const __bf16*)Yp;
  const __bf16* Y1 = Y0 + (size_t)NRP * HSD;
  b8v a0 = *(const b8v*)(Y0 + (size_t)s0 * HSD + ho);
  b8v a1 = *(const b8v*)(Y1 + (size_t)s0 * HSD + ho);
  b8v b0 = *(const b8v*)(Y0 + (size_t)s1 * HSD + ho);
  b8v b1 = *(const b8v*)(Y1 + (size_t)s1 * HSD + ho);
  float o[8];
  #pragma unroll
  for (int i = 0; i < 8; ++i)
    o[i] = w0 * ((float)a0[i] + (float)a1[i]) + w1 * ((float)b0[i] + (float)b1[i]);
  float4* op = (float4*)(out + (size_t)t * HSD + ho);
  op[0] = make_float4(o[0], o[1], o[2], o[3]);
  op[1] = make_float4(o[4], o[5], o[6], o[7]);
}

// ================= launch =================
extern "C" void kernel_launch(void* const* d_in, const int* in_sizes, int n_in,
                              void* d_out, int out_size, void* d_ws, size_t ws_size,
                              hipStream_t stream) {
  const float* x    = (const float*)d_in[0];
  const float* ew   = (const float*)d_in[1];
  const float* w1   = (const float*)d_in[2];
  const float* w2   = (const float*)d_in[3];
  const int*   eidx = (const int*)d_in[4];
  float* out = (float*)d_out;
  char* ws = (char*)d_ws;

  if (ws_size < WS_NEED) {              // sentinel: absmax ~3.4e38 => ws too small
    hipMemsetAsync(d_out, 0x7F, 8, stream);
    return;
  }

  int*   blockhist = (int*)(ws + OFF_BLOCKHIST);
  int*   blockbase = (int*)(ws + OFF_BLOCKBASE);
  int*   sched_e   = (int*)(ws + OFF_SCHED_E);
  int*   sched_r   = (int*)(ws + OFF_SCHED_R);
  int*   ntiles    = (int*)(ws + OFF_NTILES);
  int*   stok      = (int*)(ws + OFF_STOK);
  float* swt       = (float*)(ws + OFF_SWT);
  int*   slot      = (int*)(ws + OFF_SLOT);
  bf16*  xb        = (bf16*)(ws + OFF_XB);
  bf16*  w1t       = (bf16*)(ws + OFF_W1T);
  bf16*  w2t       = (bf16*)(ws + OFF_W2T);
  bf16*  Hbuf      = (bf16*)(ws + OFF_H);
  bf16*  Ypart     = (bf16*)(ws + OFF_YP);   // aliases xb/w1t (dead after GEMM1)

  moe_hist<<<64, 256, 0, stream>>>(eidx, blockhist);
  moe_plan<<<1, 256, 0, stream>>>(blockhist, blockbase, sched_e, sched_r, ntiles, stok, swt);
  moe_scatter<<<64, 256, 0, stream>>>(eidx, ew, blockbase, stok, swt, slot);

  conv_x<<<(NTOK * HSD / 4) / 256, 256, 0, stream>>>(x, xb);
  transpose_conv<<<dim3(FFND / 32, HSD / 64, NEXP), dim3(32, 8), 0, stream>>>(w1, w1t, HSD, FFND);
  transpose_conv<<<dim3(HSD / 32, FFND / 64, NEXP), dim3(32, 8), 0, stream>>>(w2, w2t, FFND, HSD);

  // GEMM1: H = gelu(X @ W1), gathered rows, K=1024
  moe_gemm<HSD, FFND, 1, true, 0><<<dim3(FFND / 128, MAXT, 1), 256, 0, stream>>>(
      xb, w1t, Hbuf, stok, sched_e, sched_r, ntiles);
  // GEMM2: Yp[z] = H @ W2 (split-K=2 partials, unweighted)
  moe_gemm<FFND, HSD, 2, false, 1><<<dim3(HSD / 128, MAXT, 2), 256, 0, stream>>>(
      Hbuf, w2t, Ypart, stok, sched_e, sched_r, ntiles);

  moe_combine<<<NTOK * HSD / 8 / 256, 256, 0, stream>>>(Ypart, swt, slot, out);
}